// Round 1
// baseline (996.498 us; speedup 1.0000x reference)
//
#include <hip/hip_runtime.h>
#include <math.h>

#define TOKENS  16384
#define HIDDEN  4096
#define NEXPERT 256
#define NGROUP  8
#define GSIZE   32   // NEXPERT / NGROUP
#define TOPKG   4
#define TOPK    8
#define ROUTED_SCALING 2.5f

// ---------------- GEMM: logits = x @ W^T ----------------
// A: [TOKENS, HIDDEN] row-major, B: [NEXPERT, HIDDEN] row-major
// C: [TOKENS, NEXPERT]
#define BM 128
#define BN 64
#define BK 32
#define LDA 132   // BM + 4 floats pad (keeps float4 alignment, breaks pow2 stride)
#define LDB 68    // BN + 4

__global__ __launch_bounds__(256, 2)
void gemm_logits(const float* __restrict__ A,
                 const float* __restrict__ B,
                 float* __restrict__ C)
{
    __shared__ float4 As4[BK * (LDA / 4)];   // float As[BK][LDA] transposed: As[k][m]
    __shared__ float4 Bs4[BK * (LDB / 4)];   // float Bs[BK][LDB] transposed: Bs[k][n]
    float* Asf = (float*)As4;
    float* Bsf = (float*)Bs4;

    const int tid  = threadIdx.x;
    const int nblk = blockIdx.x;   // 0..3   (fastest-varying -> A-tile LLC reuse)
    const int mblk = blockIdx.y;   // 0..127
    const int m0 = mblk * BM;
    const int n0 = nblk * BN;

    // compute mapping: 16x16 thread grid, micro-tile 8 rows x 4 cols
    const int tc = tid & 15;   // col group
    const int tr = tid >> 4;   // row group

    // staging mapping: 8 float4-columns per row of 32 floats
    const int f4c   = tid & 7;
    const int rbase = tid >> 3;  // 0..31

    float acc[8][4] = {};
    float cmp[8][4] = {};   // Kahan compensation (merged once per K-tile)

    float4 pa[4], pb[2];

    const float* Abase = A + (long)m0 * HIDDEN;
    const float* Bbase = B + (long)n0 * HIDDEN;

    // prefetch K-tile 0 into registers
    {
        #pragma unroll
        for (int p = 0; p < 4; ++p) {
            int row = p * 32 + rbase;
            pa[p] = *(const float4*)(Abase + (long)row * HIDDEN + f4c * 4);
        }
        #pragma unroll
        for (int p = 0; p < 2; ++p) {
            int row = p * 32 + rbase;
            pb[p] = *(const float4*)(Bbase + (long)row * HIDDEN + f4c * 4);
        }
    }

    const int NKT = HIDDEN / BK;   // 128
    for (int kt = 0; kt < NKT; ++kt) {
        // store staged registers to LDS, transposed: As[k][m], Bs[k][n]
        #pragma unroll
        for (int p = 0; p < 4; ++p) {
            int row = p * 32 + rbase;
            Asf[(f4c * 4 + 0) * LDA + row] = pa[p].x;
            Asf[(f4c * 4 + 1) * LDA + row] = pa[p].y;
            Asf[(f4c * 4 + 2) * LDA + row] = pa[p].z;
            Asf[(f4c * 4 + 3) * LDA + row] = pa[p].w;
        }
        #pragma unroll
        for (int p = 0; p < 2; ++p) {
            int row = p * 32 + rbase;
            Bsf[(f4c * 4 + 0) * LDB + row] = pb[p].x;
            Bsf[(f4c * 4 + 1) * LDB + row] = pb[p].y;
            Bsf[(f4c * 4 + 2) * LDB + row] = pb[p].z;
            Bsf[(f4c * 4 + 3) * LDB + row] = pb[p].w;
        }
        __syncthreads();

        // prefetch next K-tile while computing this one
        if (kt + 1 < NKT) {
            const int k0 = (kt + 1) * BK;
            #pragma unroll
            for (int p = 0; p < 4; ++p) {
                int row = p * 32 + rbase;
                pa[p] = *(const float4*)(Abase + (long)row * HIDDEN + k0 + f4c * 4);
            }
            #pragma unroll
            for (int p = 0; p < 2; ++p) {
                int row = p * 32 + rbase;
                pb[p] = *(const float4*)(Bbase + (long)row * HIDDEN + k0 + f4c * 4);
            }
        }

        // inner product over this K-tile into fresh accumulators
        float t_[8][4] = {};
        #pragma unroll
        for (int k = 0; k < BK; ++k) {
            float4 a0 = As4[k * (LDA / 4) + tr * 2];
            float4 a1 = As4[k * (LDA / 4) + tr * 2 + 1];
            float4 b  = Bs4[k * (LDB / 4) + tc];
            float av[8] = {a0.x, a0.y, a0.z, a0.w, a1.x, a1.y, a1.z, a1.w};
            float bv[4] = {b.x, b.y, b.z, b.w};
            #pragma unroll
            for (int i = 0; i < 8; ++i)
                #pragma unroll
                for (int j = 0; j < 4; ++j)
                    t_[i][j] = fmaf(av[i], bv[j], t_[i][j]);
        }

        // Kahan merge of tile sum into running accumulator (high accuracy:
        // near-tie top-k flips vs the numpy reference are the failure mode)
        #pragma unroll
        for (int i = 0; i < 8; ++i) {
            #pragma unroll
            for (int j = 0; j < 4; ++j) {
                float y = t_[i][j] - cmp[i][j];
                float s = acc[i][j] + y;
                cmp[i][j] = (s - acc[i][j]) - y;
                acc[i][j] = s;
            }
        }
        __syncthreads();
    }

    // epilogue: coalesced float4 stores
    #pragma unroll
    for (int i = 0; i < 8; ++i) {
        int row = m0 + tr * 8 + i;
        float4 o = make_float4(acc[i][0], acc[i][1], acc[i][2], acc[i][3]);
        *(float4*)(C + (long)row * NEXPERT + n0 + tc * 4) = o;
    }
}

// ---------------- Routing: group-limited top-k ----------------
__device__ __forceinline__ float sigmoid_acc(float x) {
    // accurate expf (NOT __expf): sigmoid rounding must stay ~1 ulp so the
    // top-k ordering matches the reference
    return 1.0f / (1.0f + expf(-x));
}

__global__ __launch_bounds__(64)
void routing_kernel(const float* __restrict__ logits,
                    const float* __restrict__ bias,
                    float* __restrict__ out_idx,
                    float* __restrict__ out_w)
{
    const int t = blockIdx.x * blockDim.x + threadIdx.x;
    if (t >= TOKENS) return;
    const float* lg = logits + (long)t * NEXPERT;

    const float NEG = -INFINITY;

    // pass 1: group scores = sum of top-2 (sigmoid(logit)+bias) per group
    float gs[NGROUP];
    #pragma unroll
    for (int g = 0; g < NGROUP; ++g) {
        float m1 = NEG, m2 = NEG;
        for (int j = 0; j < GSIZE; ++j) {
            int e = g * GSIZE + j;
            float v = sigmoid_acc(lg[e]) + bias[e];
            if (v > m1) { m2 = m1; m1 = v; }
            else if (v > m2) { m2 = v; }
        }
        gs[g] = m1 + m2;
    }

    // select top-4 groups (strict > keeps the lower index on ties, like lax.top_k)
    unsigned selmask = 0;
    #pragma unroll
    for (int r = 0; r < TOPKG; ++r) {
        float best = NEG; int bi = 0;
        #pragma unroll
        for (int g = 0; g < NGROUP; ++g) {
            bool taken = (selmask >> g) & 1u;
            if (!taken && gs[g] > best) { best = gs[g]; bi = g; }
        }
        selmask |= 1u << bi;
    }

    // pass 2: top-8 over experts in selected groups (sorted descending,
    // ties resolved to the lower expert index by iteration order + strict >)
    float rv[TOPK], pv[TOPK];
    int   ri[TOPK];
    #pragma unroll
    for (int k = 0; k < TOPK; ++k) { rv[k] = NEG; pv[k] = 0.0f; ri[k] = 0; }

    for (int g = 0; g < NGROUP; ++g) {
        if (!((selmask >> g) & 1u)) continue;
        for (int j = 0; j < GSIZE; ++j) {
            int e = g * GSIZE + j;
            float p = sigmoid_acc(lg[e]);
            float v = p + bias[e];
            if (v > rv[TOPK - 1]) {
                rv[TOPK - 1] = v; pv[TOPK - 1] = p; ri[TOPK - 1] = e;
                #pragma unroll
                for (int q = TOPK - 1; q > 0; --q) {
                    if (rv[q] > rv[q - 1]) {
                        float tv = rv[q]; rv[q] = rv[q - 1]; rv[q - 1] = tv;
                        float tp = pv[q]; pv[q] = pv[q - 1]; pv[q - 1] = tp;
                        int   ti = ri[q]; ri[q] = ri[q - 1]; ri[q - 1] = ti;
                    }
                }
            }
        }
    }

    float sum = 0.0f;
    #pragma unroll
    for (int k = 0; k < TOPK; ++k) sum += pv[k];
    float denom = sum + 1e-20f;

    #pragma unroll
    for (int k = 0; k < TOPK; ++k) {
        out_idx[(long)t * TOPK + k] = (float)ri[k];
        out_w[(long)t * TOPK + k]   = pv[k] / denom * ROUTED_SCALING;
    }
}

// ---------------- launch ----------------
extern "C" void kernel_launch(void* const* d_in, const int* in_sizes, int n_in,
                              void* d_out, int out_size, void* d_ws, size_t ws_size,
                              hipStream_t stream) {
    const float* hidden = (const float*)d_in[0];   // [TOKENS, HIDDEN]
    const float* gate_w = (const float*)d_in[1];   // [NEXPERT, HIDDEN]
    const float* bias   = (const float*)d_in[2];   // [NEXPERT]

    float* out = (float*)d_out;
    // layout: [T*8 idx][T*8 weight][T*256 logits]
    float* out_idx    = out;
    float* out_w      = out + (long)TOKENS * TOPK;
    float* out_logits = out + (long)TOKENS * TOPK * 2;

    dim3 ggrid(NEXPERT / BN, TOKENS / BM);   // (4, 128)
    gemm_logits<<<ggrid, 256, 0, stream>>>(hidden, gate_w, out_logits);

    routing_kernel<<<TOKENS / 64, 64, 0, stream>>>(out_logits, bias, out_idx, out_w);
}